// Round 1
// baseline (966.091 us; speedup 1.0000x reference)
//
#include <hip/hip_runtime.h>

typedef unsigned short u16;
typedef __bf16 bf16x8 __attribute__((ext_vector_type(8)));
typedef float f32x4 __attribute__((ext_vector_type(4)));

__device__ inline u16 f2bf(float f) {
    union { float f; unsigned u; } v; v.f = f;
    unsigned r = v.u + 0x7FFFu + ((v.u >> 16) & 1u);
    return (u16)(r >> 16);
}

__device__ inline f32x4 mfma16(bf16x8 a, bf16x8 b, f32x4 c) {
    return __builtin_amdgcn_mfma_f32_16x16x32_bf16(a, b, c, 0, 0, 0);
}

// ---------------------------------------------------------------------------
// GEMM: Y[M,N] = A[M,K] * B[N,K]^T + bias[N]   (B row-major N x K, i.e. W)
// A is fp32 (A_BF16=0) or bf16 bit-pattern in u16 (A_BF16=1). B/bias fp32.
// 128x128 tile, BK=32, 256 threads (4 waves in 2x2), mfma 16x16x32 bf16.
// ---------------------------------------------------------------------------
template<int A_BF16>
__global__ __launch_bounds__(256, 2)
void gemm_bt(const void* __restrict__ Aptr, const float* __restrict__ Bp,
             const float* __restrict__ bias, float* __restrict__ Y,
             int M, int N, int K)
{
    __shared__ u16 As[128 * 40];
    __shared__ u16 Bs[128 * 40];
    const int tid = threadIdx.x;
    const int lane = tid & 63;
    const int wv = tid >> 6;
    const int wr = wv >> 1, wc = wv & 1;
    const long m0 = (long)blockIdx.y * 128;
    const long n0 = (long)blockIdx.x * 128;
    const int cc = lane & 15, qq = lane >> 4;
    const int rs = tid >> 3;           // 0..31
    const int cs = (tid & 7) << 2;     // 0,4,..28

    f32x4 acc[4][4];
#pragma unroll
    for (int i = 0; i < 4; i++)
#pragma unroll
        for (int j = 0; j < 4; j++) acc[i][j] = (f32x4){0.f, 0.f, 0.f, 0.f};

    for (int k0 = 0; k0 < K; k0 += 32) {
#pragma unroll
        for (int it = 0; it < 4; ++it) {
            int r = rs + it * 32;
            ushort4 wa;
            if (A_BF16) {
                const u16* p = (const u16*)Aptr + (m0 + r) * (long)K + k0 + cs;
                wa = *(const ushort4*)p;
            } else {
                const float* p = (const float*)Aptr + (m0 + r) * (long)K + k0 + cs;
                float4 v = *(const float4*)p;
                wa.x = f2bf(v.x); wa.y = f2bf(v.y); wa.z = f2bf(v.z); wa.w = f2bf(v.w);
            }
            *(ushort4*)&As[r * 40 + cs] = wa;

            const float* pb = Bp + (n0 + r) * (long)K + k0 + cs;
            float4 vb = *(const float4*)pb;
            ushort4 wb;
            wb.x = f2bf(vb.x); wb.y = f2bf(vb.y); wb.z = f2bf(vb.z); wb.w = f2bf(vb.w);
            *(ushort4*)&Bs[r * 40 + cs] = wb;
        }
        __syncthreads();
        bf16x8 af[4], bfr[4];
#pragma unroll
        for (int i = 0; i < 4; i++)
            af[i] = *(const bf16x8*)&As[(wr * 64 + i * 16 + cc) * 40 + qq * 8];
#pragma unroll
        for (int j = 0; j < 4; j++)
            bfr[j] = *(const bf16x8*)&Bs[(wc * 64 + j * 16 + cc) * 40 + qq * 8];
#pragma unroll
        for (int i = 0; i < 4; i++)
#pragma unroll
            for (int j = 0; j < 4; j++)
                acc[i][j] = mfma16(af[i], bfr[j], acc[i][j]);
        __syncthreads();
    }

#pragma unroll
    for (int i = 0; i < 4; i++) {
#pragma unroll
        for (int j = 0; j < 4; j++) {
            long row = m0 + wr * 64 + i * 16 + qq * 4;
            long col = n0 + wc * 64 + j * 16 + cc;
            float bv = bias[col];
#pragma unroll
            for (int r2 = 0; r2 < 4; r2++)
                Y[(row + r2) * (long)N + col] = acc[i][j][r2] + bv;
        }
    }
}

// ---------------------------------------------------------------------------
// YaRN RoPE + relayout to bf16 [B, nh, S, 64].  Yt is fp32 [B*S, nh*64].
// One thread per (m, head, d<32): handles the (d, d+32) rotation pair.
// ---------------------------------------------------------------------------
__global__ __launch_bounds__(256)
void rope_qk(const float* __restrict__ Yt, const int* __restrict__ pid,
             u16* __restrict__ Out, int nh, int lg)
{
    int idx = blockIdx.x * 256 + threadIdx.x;
    int d = idx & 31;
    int t2 = idx >> 5;
    int hh = t2 & (nh - 1);
    int m = t2 >> lg;
    const float* row = Yt + (size_t)m * ((size_t)nh << 6) + (hh << 6);
    float x1 = row[d], x2 = row[d + 32];
    int pos = pid[m];
    // YaRN-scaled frequency (fp32, matches numpy table to ~1e-7 rel)
    float ex = (float)d * (1.0f / 32.0f);            // 2d/64
    float freq = powf(10000.0f, -ex);
    float wl = 6.2831853071795864f / freq;
    float tt = (wl - 32.0f) * (1.0f / 992.0f);
    tt = fminf(fmaxf(tt, 0.0f), 1.0f);
    float eff = freq * (1.0f - tt) + 0.25f * freq * tt;
    float ang = ((float)pos * eff) * 1.1386294361119891f;  // * concentration
    float sv = sinf(ang), cv = cosf(ang);
    int b = m >> 11, s = m & 2047;                   // S = 2048
    u16* o = Out + (((size_t)(b * nh + hh)) * 2048 + s) * 64;
    o[d]      = f2bf(x1 * cv - x2 * sv);
    o[d + 32] = f2bf(x2 * cv + x1 * sv);
}

// ---------------------------------------------------------------------------
// V: fp32 [B*S, 512] -> bf16 transposed [B*NKV, 64, S]
// ---------------------------------------------------------------------------
__global__ __launch_bounds__(256)
void v_transpose(const float* __restrict__ Vtmp, u16* __restrict__ VbT)
{
    __shared__ float tile[64][65];
    int s0 = blockIdx.x * 64;
    int bkv = blockIdx.y;
    int b = bkv >> 3, kv = bkv & 7;
    int t = threadIdx.x;
#pragma unroll
    for (int it = 0; it < 16; ++it) {
        int idx = t + it * 256;
        int s = idx >> 6, d = idx & 63;
        tile[s][d] = Vtmp[((size_t)(b * 2048 + s0 + s)) * 512 + kv * 64 + d];
    }
    __syncthreads();
#pragma unroll
    for (int it = 0; it < 16; ++it) {
        int idx = t + it * 256;
        int d = idx >> 6, s = idx & 63;
        VbT[((size_t)(bkv * 64 + d)) * 2048 + s0 + s] = f2bf(tile[s][d]);
    }
}

// ---------------------------------------------------------------------------
// Sliding-window attention with sink.  One block per (b, kv, 16-query tile).
// 4 waves = 4 query-heads of the group.  Whole 143-key window staged at once
// (TK=160 incl. zero pad) -> QK^T (MFMA) -> masked softmax w/ sink (shuffle
// reduce across the 16 lanes of a quad) -> P (bf16, scaled by 1/denom) via
// LDS -> PV (MFMA) -> ctx bf16 [B*S, NH*64].
// ---------------------------------------------------------------------------
#define TK  160
#define LKS 72
#define LVS 168

__global__ __launch_bounds__(256, 2)
void attn_win(const u16* __restrict__ Qb, const u16* __restrict__ Kb,
              const u16* __restrict__ VbT, const float* __restrict__ sinks,
              u16* __restrict__ Ctx)
{
    __shared__ u16 KsPs[TK * LKS];   // K tile; reused for P after scores
    __shared__ u16 Vst[64 * LVS];    // V^T tile
    const int S = 2048;
    const int tid = threadIdx.x;
    const int lane = tid & 63;
    const int w = tid >> 6;            // head-in-group g
    const int cc = lane & 15, qq = lane >> 4;
    const int blk = blockIdx.x;
    const int qt = blk & 127;          // S/16
    const int bkv = blk >> 7;          // b*8+kv
    const int b = bkv >> 3, kv = bkv & 7;
    const int q0 = qt * 16;
    const int ks0 = q0 - 127;
    const int h = kv * 4 + w;

    // stage K rows [TK][64]
    const u16* KbBase = Kb + ((size_t)bkv * S) * 64;
    for (int idx = tid; idx < TK * 64; idx += 256) {
        int kk = idx >> 6, d = idx & 63;
        int sk = ks0 + kk;
        u16 v = 0;
        if (sk >= 0 && sk < S) v = KbBase[(size_t)sk * 64 + d];
        KsPs[kk * LKS + d] = v;
    }
    // stage V^T rows [64][TK]
    const u16* VtBase = VbT + ((size_t)bkv * 64) * S;
    for (int idx = tid; idx < 64 * TK; idx += 256) {
        int d = idx / TK, kk = idx % TK;
        int sk = ks0 + kk;
        u16 v = 0;
        if (sk >= 0 && sk < S) v = VtBase[(size_t)d * S + sk];
        Vst[d * LVS + kk] = v;
    }
    __syncthreads();

    // Q fragments (K-dim 64 = 2 mfma k-steps)
    const u16* Qrow = Qb + (((size_t)(b * 32 + h) * S) + q0 + cc) * 64;
    bf16x8 aq0 = *(const bf16x8*)(Qrow + qq * 8);
    bf16x8 aq1 = *(const bf16x8*)(Qrow + 32 + qq * 8);

    f32x4 sc[10];
#pragma unroll
    for (int j = 0; j < 10; j++) sc[j] = (f32x4){0.f, 0.f, 0.f, 0.f};
#pragma unroll
    for (int j = 0; j < 10; j++) {
        bf16x8 b0 = *(const bf16x8*)&KsPs[(j * 16 + cc) * LKS + qq * 8];
        bf16x8 b1 = *(const bf16x8*)&KsPs[(j * 16 + cc) * LKS + 32 + qq * 8];
        sc[j] = mfma16(aq0, b0, sc[j]);
        sc[j] = mfma16(aq1, b1, sc[j]);
    }

    __syncthreads();   // everyone done reading K before P overwrites it

    const float sinkv = sinks[h];
    float pv[10][4];
#pragma unroll
    for (int r = 0; r < 4; r++) {
        int qi = qq * 4 + r;
        float sval[10];
        float mx = -3.0e38f;
#pragma unroll
        for (int j = 0; j < 10; j++) {
            int kk = j * 16 + cc;
            float s = sc[j][r] * 0.125f;     // 1/sqrt(64)
            bool ok = (kk >= qi) && (kk <= qi + 127) && (ks0 + kk >= 0);
            s = ok ? s : -3.0e38f;
            sval[j] = s;
            mx = fmaxf(mx, s);
        }
#pragma unroll
        for (int off = 1; off < 16; off <<= 1) mx = fmaxf(mx, __shfl_xor(mx, off));
        mx = fmaxf(mx, sinkv);
        float sum = 0.f;
#pragma unroll
        for (int j = 0; j < 10; j++) {
            float p = __expf(sval[j] - mx);   // masked -> exp(-huge) = 0
            sval[j] = p;
            sum += p;
        }
#pragma unroll
        for (int off = 1; off < 16; off <<= 1) sum += __shfl_xor(sum, off);
        float rden = 1.0f / (sum + __expf(sinkv - mx));
#pragma unroll
        for (int j = 0; j < 10; j++) pv[j][r] = sval[j] * rden;
    }
    // write P (bf16) into KsPs, rows = w*16+qi, stride LVS
#pragma unroll
    for (int r = 0; r < 4; r++) {
        int qi = qq * 4 + r;
#pragma unroll
        for (int j = 0; j < 10; j++)
            KsPs[(w * 16 + qi) * LVS + j * 16 + cc] = f2bf(pv[j][r]);
    }
    __syncthreads();

    // PV: ctx[16 x 64] per wave, K-dim = TK=160 -> 5 k-steps
    f32x4 o[4];
#pragma unroll
    for (int jt = 0; jt < 4; jt++) o[jt] = (f32x4){0.f, 0.f, 0.f, 0.f};
#pragma unroll
    for (int ks = 0; ks < 5; ks++) {
        bf16x8 ap = *(const bf16x8*)&KsPs[(w * 16 + cc) * LVS + ks * 32 + qq * 8];
#pragma unroll
        for (int jt = 0; jt < 4; jt++) {
            bf16x8 bv = *(const bf16x8*)&Vst[(jt * 16 + cc) * LVS + ks * 32 + qq * 8];
            o[jt] = mfma16(ap, bv, o[jt]);
        }
    }
#pragma unroll
    for (int jt = 0; jt < 4; jt++) {
#pragma unroll
        for (int r = 0; r < 4; r++) {
            int qi = qq * 4 + r;
            size_t off = ((size_t)(b * S + q0 + qi)) * 2048 + h * 64 + jt * 16 + cc;
            Ctx[off] = f2bf(o[jt][r]);
        }
    }
}

// ---------------------------------------------------------------------------
extern "C" void kernel_launch(void* const* d_in, const int* in_sizes, int n_in,
                              void* d_out, int out_size, void* d_ws, size_t ws_size,
                              hipStream_t stream)
{
    const float* x    = (const float*)d_in[0];
    const float* Wq   = (const float*)d_in[1];
    const float* bq   = (const float*)d_in[2];
    const float* Wk   = (const float*)d_in[3];
    const float* bk   = (const float*)d_in[4];
    const float* Wv   = (const float*)d_in[5];
    const float* bv   = (const float*)d_in[6];
    const float* Wo   = (const float*)d_in[7];
    const float* bo   = (const float*)d_in[8];
    const float* sinks = (const float*)d_in[9];
    const int*   pid  = (const int*)d_in[10];
    float* out = (float*)d_out;

    char* ws = (char*)d_ws;
    float* Qtmp = (float*)ws;                       // 33,554,432 B (fp32 Q pre-rope)
    u16*   Ctx  = (u16*)ws;                         // alias (Qtmp dead after rope)
    float* Ktmp = (float*)(ws + 33554432);          //  8,388,608 B
    float* Vtmp = (float*)(ws + 41943040);          //  8,388,608 B
    u16*   Qb   = (u16*)(ws + 50331648);            // 16,777,216 B
    u16*   Kb   = (u16*)(ws + 67108864);            //  4,194,304 B
    u16*   VbT  = (u16*)(ws + 71303168);            //  4,194,304 B  (total 72 MiB)

    const int M = 4096;
    gemm_bt<0><<<dim3(16, 32), 256, 0, stream>>>(x, Wq, bq, Qtmp, M, 2048, 2048);
    gemm_bt<0><<<dim3(4, 32),  256, 0, stream>>>(x, Wk, bk, Ktmp, M, 512, 2048);
    gemm_bt<0><<<dim3(4, 32),  256, 0, stream>>>(x, Wv, bv, Vtmp, M, 512, 2048);
    rope_qk<<<(M * 32 * 32) / 256, 256, 0, stream>>>(Qtmp, pid, Qb, 32, 5);
    rope_qk<<<(M * 8 * 32) / 256, 256, 0, stream>>>(Ktmp, pid, Kb, 8, 3);
    v_transpose<<<dim3(32, 16), 256, 0, stream>>>(Vtmp, VbT);
    attn_win<<<2048, 256, 0, stream>>>(Qb, Kb, VbT, sinks, Ctx);
    gemm_bt<1><<<dim3(16, 32), 256, 0, stream>>>(Ctx, Wo, bo, out, M, 2048, 2048);
}

// Round 2
// 360.154 us; speedup vs baseline: 2.6824x; 2.6824x over previous
//
#include <hip/hip_runtime.h>

typedef unsigned short u16;
typedef __bf16 bf16x8 __attribute__((ext_vector_type(8)));
typedef float f32x4 __attribute__((ext_vector_type(4)));

__device__ inline u16 f2bf(float f) {
    union { float f; unsigned u; } v; v.f = f;
    unsigned r = v.u + 0x7FFFu + ((v.u >> 16) & 1u);
    return (u16)(r >> 16);
}
__device__ inline float bf2f(u16 h) {
    union { unsigned u; float f; } v; v.u = ((unsigned)h) << 16;
    return v.f;
}
__device__ inline f32x4 mfma16(bf16x8 a, bf16x8 b, f32x4 c) {
    return __builtin_amdgcn_mfma_f32_16x16x32_bf16(a, b, c, 0, 0, 0);
}
__device__ inline void gload_lds16(const u16* g, u16* l) {
    __builtin_amdgcn_global_load_lds(
        (const __attribute__((address_space(1))) void*)g,
        (__attribute__((address_space(3))) void*)l, 16, 0, 0);
}

// ---------------------------------------------------------------------------
// fp32 -> bf16 pack (n multiple of 4)
// ---------------------------------------------------------------------------
__global__ __launch_bounds__(256)
void pack_bf16(const float* __restrict__ src, u16* __restrict__ dst, int n)
{
    int i = (blockIdx.x * 256 + threadIdx.x) * 4;
    if (i >= n) return;
    float4 v = *(const float4*)(src + i);
    ushort4 w;
    w.x = f2bf(v.x); w.y = f2bf(v.y); w.z = f2bf(v.z); w.w = f2bf(v.w);
    *(ushort4*)(dst + i) = w;
}

__global__ __launch_bounds__(256)
void concat_bias(const float* __restrict__ bq, const float* __restrict__ bk,
                 const float* __restrict__ bv, float* __restrict__ dst)
{
    int i = blockIdx.x * 256 + threadIdx.x;   // 3072 total
    float v;
    if (i < 2048) v = bq[i];
    else if (i < 2560) v = bk[i - 2048];
    else v = bv[i - 2560];
    dst[i] = v;
}

// ---------------------------------------------------------------------------
// GEMM: Y[M,N] = A[M,K] * B[N,K]^T + bias[N],  A/B bf16, out fp32 or bf16.
// m97 structure: 128x128 tile, BK=32, global_load_lds width=16 staging,
// XOR-swizzled LDS columns (swizzle folded into the GLOBAL address so the
// wave-uniform-base+lane*16 LDS write pattern stays legal).
//   LDS (row, colsw) holds global col8 = colsw ^ ((row>>1)&3).
// ---------------------------------------------------------------------------
template<int OUT_BF16>
__global__ __launch_bounds__(256, 2)
void gemm_bb(const u16* __restrict__ A, const u16* __restrict__ B,
             const float* __restrict__ bias, void* __restrict__ Yv,
             int M, int N, int K)
{
    __shared__ u16 As[128 * 32];
    __shared__ u16 Bs[128 * 32];
    const int tid = threadIdx.x;
    const int lane = tid & 63;
    const int wv = tid >> 6;
    const int wr = wv >> 1, wc = wv & 1;
    const long m0 = (long)blockIdx.y * 128;
    const long n0 = (long)blockIdx.x * 128;
    const int cc = lane & 15, qq = lane >> 4;

    // staging: wave wv owns 1KB chunks {2wv, 2wv+1}; lane covers
    // row = 16*chunk + (lane>>2), global col8 = (lane&3) ^ ((lane>>3)&3)
    const int srow = (2 * wv) * 16 + (lane >> 2);
    const int gcol = (((lane & 3) ^ ((lane >> 3) & 3)) << 3);
    const u16* Ag0 = A + (m0 + srow) * (long)K + gcol;
    const u16* Ag1 = A + (m0 + srow + 16) * (long)K + gcol;
    const u16* Bg0 = B + (n0 + srow) * (long)K + gcol;
    const u16* Bg1 = B + (n0 + srow + 16) * (long)K + gcol;
    u16* AsW0 = &As[(2 * wv) * 512];
    u16* AsW1 = AsW0 + 512;
    u16* BsW0 = &Bs[(2 * wv) * 512];
    u16* BsW1 = BsW0 + 512;

    // fragment-read swizzled column (row = ...+cc, (row>>1)&3 == (cc>>1)&3)
    const int csw = (qq ^ ((cc >> 1) & 3)) << 3;

    f32x4 acc[4][4];
#pragma unroll
    for (int i = 0; i < 4; i++)
#pragma unroll
        for (int j = 0; j < 4; j++) acc[i][j] = (f32x4){0.f, 0.f, 0.f, 0.f};

    for (int k0 = 0; k0 < K; k0 += 32) {
        gload_lds16(Ag0 + k0, AsW0);
        gload_lds16(Ag1 + k0, AsW1);
        gload_lds16(Bg0 + k0, BsW0);
        gload_lds16(Bg1 + k0, BsW1);
        __syncthreads();
        bf16x8 af[4], bfr[4];
#pragma unroll
        for (int i = 0; i < 4; i++)
            af[i] = *(const bf16x8*)&As[(wr * 64 + i * 16 + cc) * 32 + csw];
#pragma unroll
        for (int j = 0; j < 4; j++)
            bfr[j] = *(const bf16x8*)&Bs[(wc * 64 + j * 16 + cc) * 32 + csw];
#pragma unroll
        for (int i = 0; i < 4; i++)
#pragma unroll
            for (int j = 0; j < 4; j++)
                acc[i][j] = mfma16(af[i], bfr[j], acc[i][j]);
        __syncthreads();
    }

#pragma unroll
    for (int i = 0; i < 4; i++) {
#pragma unroll
        for (int j = 0; j < 4; j++) {
            long row = m0 + wr * 64 + i * 16 + qq * 4;
            long col = n0 + wc * 64 + j * 16 + cc;
            float bv = bias[col];
#pragma unroll
            for (int r2 = 0; r2 < 4; r2++) {
                float v = acc[i][j][r2] + bv;
                if (OUT_BF16)
                    ((u16*)Yv)[(row + r2) * (long)N + col] = f2bf(v);
                else
                    ((float*)Yv)[(row + r2) * (long)N + col] = v;
            }
        }
    }
}

// ---------------------------------------------------------------------------
// YaRN RoPE + relayout to bf16 [B, nh, S, 64].  Yt is bf16 [B*S, 3072],
// head block at column offset coff.  One thread per (m, head, d<32).
// ---------------------------------------------------------------------------
__global__ __launch_bounds__(256)
void rope_qk(const u16* __restrict__ Yt, const int* __restrict__ pid,
             u16* __restrict__ Out, int nh, int lg, int coff)
{
    int idx = blockIdx.x * 256 + threadIdx.x;
    int d = idx & 31;
    int t2 = idx >> 5;
    int hh = t2 & (nh - 1);
    int m = t2 >> lg;
    const u16* row = Yt + (size_t)m * 3072 + coff + (hh << 6);
    float x1 = bf2f(row[d]), x2 = bf2f(row[d + 32]);
    int pos = pid[m];
    float ex = (float)d * (1.0f / 32.0f);
    float freq = powf(10000.0f, -ex);
    float wl = 6.2831853071795864f / freq;
    float tt = (wl - 32.0f) * (1.0f / 992.0f);
    tt = fminf(fmaxf(tt, 0.0f), 1.0f);
    float eff = freq * (1.0f - tt) + 0.25f * freq * tt;
    float ang = ((float)pos * eff) * 1.1386294361119891f;
    float sv = sinf(ang), cv = cosf(ang);
    int b = m >> 11, s = m & 2047;
    u16* o = Out + (((size_t)(b * nh + hh)) * 2048 + s) * 64;
    o[d]      = f2bf(x1 * cv - x2 * sv);
    o[d + 32] = f2bf(x2 * cv + x1 * sv);
}

// ---------------------------------------------------------------------------
// V: bf16 [B*S, 3072] (cols 2560..3071) -> bf16 transposed [B*NKV, 64, S]
// ---------------------------------------------------------------------------
__global__ __launch_bounds__(256)
void v_transpose(const u16* __restrict__ Vt, u16* __restrict__ VbT)
{
    __shared__ u16 tile[64][66];
    int s0 = blockIdx.x * 64;
    int bkv = blockIdx.y;
    int b = bkv >> 3, kv = bkv & 7;
    int t = threadIdx.x;
#pragma unroll
    for (int it = 0; it < 16; ++it) {
        int idx = t + it * 256;
        int s = idx >> 6, d = idx & 63;
        tile[s][d] = Vt[((size_t)(b * 2048 + s0 + s)) * 3072 + 2560 + kv * 64 + d];
    }
    __syncthreads();
#pragma unroll
    for (int it = 0; it < 16; ++it) {
        int idx = t + it * 256;
        int d = idx >> 6, s = idx & 63;
        VbT[((size_t)(bkv * 64 + d)) * 2048 + s0 + s] = tile[s][d];
    }
}

// ---------------------------------------------------------------------------
// Sliding-window attention with sink (unchanged from round 1).
// ---------------------------------------------------------------------------
#define TK  160
#define LKS 72
#define LVS 168

__global__ __launch_bounds__(256, 2)
void attn_win(const u16* __restrict__ Qb, const u16* __restrict__ Kb,
              const u16* __restrict__ VbT, const float* __restrict__ sinks,
              u16* __restrict__ Ctx)
{
    __shared__ u16 KsPs[TK * LKS];
    __shared__ u16 Vst[64 * LVS];
    const int S = 2048;
    const int tid = threadIdx.x;
    const int lane = tid & 63;
    const int w = tid >> 6;
    const int cc = lane & 15, qq = lane >> 4;
    const int blk = blockIdx.x;
    const int qt = blk & 127;
    const int bkv = blk >> 7;
    const int b = bkv >> 3, kv = bkv & 7;
    const int q0 = qt * 16;
    const int ks0 = q0 - 127;
    const int h = kv * 4 + w;

    const u16* KbBase = Kb + ((size_t)bkv * S) * 64;
    for (int idx = tid; idx < TK * 64; idx += 256) {
        int kk = idx >> 6, d = idx & 63;
        int sk = ks0 + kk;
        u16 v = 0;
        if (sk >= 0 && sk < S) v = KbBase[(size_t)sk * 64 + d];
        KsPs[kk * LKS + d] = v;
    }
    const u16* VtBase = VbT + ((size_t)bkv * 64) * S;
    for (int idx = tid; idx < 64 * TK; idx += 256) {
        int d = idx / TK, kk = idx % TK;
        int sk = ks0 + kk;
        u16 v = 0;
        if (sk >= 0 && sk < S) v = VtBase[(size_t)d * S + sk];
        Vst[d * LVS + kk] = v;
    }
    __syncthreads();

    const u16* Qrow = Qb + (((size_t)(b * 32 + h) * S) + q0 + cc) * 64;
    bf16x8 aq0 = *(const bf16x8*)(Qrow + qq * 8);
    bf16x8 aq1 = *(const bf16x8*)(Qrow + 32 + qq * 8);

    f32x4 sc[10];
#pragma unroll
    for (int j = 0; j < 10; j++) sc[j] = (f32x4){0.f, 0.f, 0.f, 0.f};
#pragma unroll
    for (int j = 0; j < 10; j++) {
        bf16x8 b0 = *(const bf16x8*)&KsPs[(j * 16 + cc) * LKS + qq * 8];
        bf16x8 b1 = *(const bf16x8*)&KsPs[(j * 16 + cc) * LKS + 32 + qq * 8];
        sc[j] = mfma16(aq0, b0, sc[j]);
        sc[j] = mfma16(aq1, b1, sc[j]);
    }

    __syncthreads();

    const float sinkv = sinks[h];
    float pv[10][4];
#pragma unroll
    for (int r = 0; r < 4; r++) {
        int qi = qq * 4 + r;
        float sval[10];
        float mx = -3.0e38f;
#pragma unroll
        for (int j = 0; j < 10; j++) {
            int kk = j * 16 + cc;
            float s = sc[j][r] * 0.125f;
            bool ok = (kk >= qi) && (kk <= qi + 127) && (ks0 + kk >= 0);
            s = ok ? s : -3.0e38f;
            sval[j] = s;
            mx = fmaxf(mx, s);
        }
#pragma unroll
        for (int off = 1; off < 16; off <<= 1) mx = fmaxf(mx, __shfl_xor(mx, off));
        mx = fmaxf(mx, sinkv);
        float sum = 0.f;
#pragma unroll
        for (int j = 0; j < 10; j++) {
            float p = __expf(sval[j] - mx);
            sval[j] = p;
            sum += p;
        }
#pragma unroll
        for (int off = 1; off < 16; off <<= 1) sum += __shfl_xor(sum, off);
        float rden = 1.0f / (sum + __expf(sinkv - mx));
#pragma unroll
        for (int j = 0; j < 10; j++) pv[j][r] = sval[j] * rden;
    }
#pragma unroll
    for (int r = 0; r < 4; r++) {
        int qi = qq * 4 + r;
#pragma unroll
        for (int j = 0; j < 10; j++)
            KsPs[(w * 16 + qi) * LVS + j * 16 + cc] = f2bf(pv[j][r]);
    }
    __syncthreads();

    f32x4 o[4];
#pragma unroll
    for (int jt = 0; jt < 4; jt++) o[jt] = (f32x4){0.f, 0.f, 0.f, 0.f};
#pragma unroll
    for (int ks = 0; ks < 5; ks++) {
        bf16x8 ap = *(const bf16x8*)&KsPs[(w * 16 + cc) * LVS + ks * 32 + qq * 8];
#pragma unroll
        for (int jt = 0; jt < 4; jt++) {
            bf16x8 bv = *(const bf16x8*)&Vst[(jt * 16 + cc) * LVS + ks * 32 + qq * 8];
            o[jt] = mfma16(ap, bv, o[jt]);
        }
    }
#pragma unroll
    for (int jt = 0; jt < 4; jt++) {
#pragma unroll
        for (int r = 0; r < 4; r++) {
            int qi = qq * 4 + r;
            size_t off = ((size_t)(b * S + q0 + qi)) * 2048 + h * 64 + jt * 16 + cc;
            Ctx[off] = f2bf(o[jt][r]);
        }
    }
}

// ---------------------------------------------------------------------------
extern "C" void kernel_launch(void* const* d_in, const int* in_sizes, int n_in,
                              void* d_out, int out_size, void* d_ws, size_t ws_size,
                              hipStream_t stream)
{
    const float* x    = (const float*)d_in[0];
    const float* Wq   = (const float*)d_in[1];
    const float* bq   = (const float*)d_in[2];
    const float* Wk   = (const float*)d_in[3];
    const float* bk   = (const float*)d_in[4];
    const float* Wv   = (const float*)d_in[5];
    const float* bv   = (const float*)d_in[6];
    const float* Wo   = (const float*)d_in[7];
    const float* bo   = (const float*)d_in[8];
    const float* sinks = (const float*)d_in[9];
    const int*   pid  = (const int*)d_in[10];
    float* out = (float*)d_out;

    char* ws = (char*)d_ws;
    u16*   Wqkvb = (u16*)ws;                         // 12,582,912 B
    u16*   Wob   = (u16*)(ws + 12582912);            //  8,388,608 B
    u16*   xQb   = (u16*)(ws + 20971520);            // 16,777,216 B (xb, then Qb)
    u16*   QKV   = (u16*)(ws + 37748736);            // 25,165,824 B (then Ctx)
    u16*   Kb    = (u16*)(ws + 62914560);            //  4,194,304 B
    u16*   VbT   = (u16*)(ws + 67108864);            //  4,194,304 B
    float* bqkv  = (float*)(ws + 71303168);          //     12,288 B

    const int M = 4096;
    // pack to bf16
    pack_bf16<<<8192, 256, 0, stream>>>(x,  xQb, 8388608);
    pack_bf16<<<4096, 256, 0, stream>>>(Wq, Wqkvb, 4194304);
    pack_bf16<<<1024, 256, 0, stream>>>(Wk, Wqkvb + 4194304, 1048576);
    pack_bf16<<<1024, 256, 0, stream>>>(Wv, Wqkvb + 5242880, 1048576);
    pack_bf16<<<4096, 256, 0, stream>>>(Wo, Wob, 4194304);
    concat_bias<<<12, 256, 0, stream>>>(bq, bk, bv, bqkv);

    // fused QKV projection: [4096,2048] x [3072,2048]^T -> bf16 [4096,3072]
    gemm_bb<1><<<dim3(24, 32), 256, 0, stream>>>(xQb, Wqkvb, bqkv, QKV, M, 3072, 2048);

    rope_qk<<<16384, 256, 0, stream>>>(QKV, pid, xQb, 32, 5, 0);      // Qb aliases xb
    rope_qk<<<4096,  256, 0, stream>>>(QKV, pid, Kb, 8, 3, 2048);
    v_transpose<<<dim3(32, 16), 256, 0, stream>>>(QKV, VbT);

    attn_win<<<2048, 256, 0, stream>>>(xQb, Kb, VbT, sinks, QKV);     // Ctx aliases QKV

    // output projection: [4096,2048] x [2048,2048]^T + bo -> fp32 out
    gemm_bb<0><<<dim3(16, 32), 256, 0, stream>>>(QKV, Wob, bo, out, M, 2048, 2048);
}

// Round 3
// 297.866 us; speedup vs baseline: 3.2434x; 1.2091x over previous
//
#include <hip/hip_runtime.h>

typedef unsigned short u16;
typedef __bf16 bf16x8 __attribute__((ext_vector_type(8)));
typedef float f32x4 __attribute__((ext_vector_type(4)));
typedef unsigned short us8 __attribute__((ext_vector_type(8)));

__device__ inline u16 f2bf(float f) {
    union { float f; unsigned u; } v; v.f = f;
    unsigned r = v.u + 0x7FFFu + ((v.u >> 16) & 1u);
    return (u16)(r >> 16);
}
__device__ inline float bf2f(u16 h) {
    union { unsigned u; float f; } v; v.u = ((unsigned)h) << 16;
    return v.f;
}
__device__ inline f32x4 mfma16(bf16x8 a, bf16x8 b, f32x4 c) {
    return __builtin_amdgcn_mfma_f32_16x16x32_bf16(a, b, c, 0, 0, 0);
}
__device__ inline void gload_lds16(const u16* g, u16* l) {
    __builtin_amdgcn_global_load_lds(
        (const __attribute__((address_space(1))) void*)g,
        (__attribute__((address_space(3))) void*)l, 16, 0, 0);
}

// ---------------------------------------------------------------------------
// fp32 -> bf16 pack (n multiple of 4)
// ---------------------------------------------------------------------------
__global__ __launch_bounds__(256)
void pack_bf16(const float* __restrict__ src, u16* __restrict__ dst, int n)
{
    int i = (blockIdx.x * 256 + threadIdx.x) * 4;
    if (i >= n) return;
    float4 v = *(const float4*)(src + i);
    ushort4 w;
    w.x = f2bf(v.x); w.y = f2bf(v.y); w.z = f2bf(v.z); w.w = f2bf(v.w);
    *(ushort4*)(dst + i) = w;
}

__global__ __launch_bounds__(256)
void concat_bias(const float* __restrict__ bq, const float* __restrict__ bk,
                 const float* __restrict__ bv, float* __restrict__ dst)
{
    int i = blockIdx.x * 256 + threadIdx.x;   // 3072 total
    float v;
    if (i < 2048) v = bq[i];
    else if (i < 2560) v = bk[i - 2048];
    else v = bv[i - 2560];
    dst[i] = v;
}

// ---------------------------------------------------------------------------
// GEMM: Y[M,N] = A[M,K] * B[N,K]^T + bias[N],  A/B bf16, out fp32 or bf16.
// m97 structure: 128x128 tile, BK=32, global_load_lds width=16 staging,
// XOR-swizzled LDS columns (swizzle folded into the GLOBAL address so the
// wave-uniform-base+lane*16 LDS write pattern stays legal).
// ---------------------------------------------------------------------------
template<int OUT_BF16>
__global__ __launch_bounds__(256, 2)
void gemm_bb(const u16* __restrict__ A, const u16* __restrict__ B,
             const float* __restrict__ bias, void* __restrict__ Yv,
             int M, int N, int K)
{
    __shared__ u16 As[128 * 32];
    __shared__ u16 Bs[128 * 32];
    const int tid = threadIdx.x;
    const int lane = tid & 63;
    const int wv = tid >> 6;
    const int wr = wv >> 1, wc = wv & 1;
    const long m0 = (long)blockIdx.y * 128;
    const long n0 = (long)blockIdx.x * 128;
    const int cc = lane & 15, qq = lane >> 4;

    const int srow = (2 * wv) * 16 + (lane >> 2);
    const int gcol = (((lane & 3) ^ ((lane >> 3) & 3)) << 3);
    const u16* Ag0 = A + (m0 + srow) * (long)K + gcol;
    const u16* Ag1 = A + (m0 + srow + 16) * (long)K + gcol;
    const u16* Bg0 = B + (n0 + srow) * (long)K + gcol;
    const u16* Bg1 = B + (n0 + srow + 16) * (long)K + gcol;
    u16* AsW0 = &As[(2 * wv) * 512];
    u16* AsW1 = AsW0 + 512;
    u16* BsW0 = &Bs[(2 * wv) * 512];
    u16* BsW1 = BsW0 + 512;

    const int csw = (qq ^ ((cc >> 1) & 3)) << 3;

    f32x4 acc[4][4];
#pragma unroll
    for (int i = 0; i < 4; i++)
#pragma unroll
        for (int j = 0; j < 4; j++) acc[i][j] = (f32x4){0.f, 0.f, 0.f, 0.f};

    for (int k0 = 0; k0 < K; k0 += 32) {
        gload_lds16(Ag0 + k0, AsW0);
        gload_lds16(Ag1 + k0, AsW1);
        gload_lds16(Bg0 + k0, BsW0);
        gload_lds16(Bg1 + k0, BsW1);
        __syncthreads();
        bf16x8 af[4], bfr[4];
#pragma unroll
        for (int i = 0; i < 4; i++)
            af[i] = *(const bf16x8*)&As[(wr * 64 + i * 16 + cc) * 32 + csw];
#pragma unroll
        for (int j = 0; j < 4; j++)
            bfr[j] = *(const bf16x8*)&Bs[(wc * 64 + j * 16 + cc) * 32 + csw];
#pragma unroll
        for (int i = 0; i < 4; i++)
#pragma unroll
            for (int j = 0; j < 4; j++)
                acc[i][j] = mfma16(af[i], bfr[j], acc[i][j]);
        __syncthreads();
    }

#pragma unroll
    for (int i = 0; i < 4; i++) {
#pragma unroll
        for (int j = 0; j < 4; j++) {
            long row = m0 + wr * 64 + i * 16 + qq * 4;
            long col = n0 + wc * 64 + j * 16 + cc;
            float bv = bias[col];
#pragma unroll
            for (int r2 = 0; r2 < 4; r2++) {
                float v = acc[i][j][r2] + bv;
                if (OUT_BF16)
                    ((u16*)Yv)[(row + r2) * (long)N + col] = f2bf(v);
                else
                    ((float*)Yv)[(row + r2) * (long)N + col] = v;
            }
        }
    }
}

// ---------------------------------------------------------------------------
// YaRN RoPE + relayout to bf16 [B, nh, S, 64].  Yt is bf16 [B*S, 3072].
// ---------------------------------------------------------------------------
__global__ __launch_bounds__(256)
void rope_qk(const u16* __restrict__ Yt, const int* __restrict__ pid,
             u16* __restrict__ Out, int nh, int lg, int coff)
{
    int idx = blockIdx.x * 256 + threadIdx.x;
    int d = idx & 31;
    int t2 = idx >> 5;
    int hh = t2 & (nh - 1);
    int m = t2 >> lg;
    const u16* row = Yt + (size_t)m * 3072 + coff + (hh << 6);
    float x1 = bf2f(row[d]), x2 = bf2f(row[d + 32]);
    int pos = pid[m];
    float ex = (float)d * (1.0f / 32.0f);
    float freq = powf(10000.0f, -ex);
    float wl = 6.2831853071795864f / freq;
    float tt = (wl - 32.0f) * (1.0f / 992.0f);
    tt = fminf(fmaxf(tt, 0.0f), 1.0f);
    float eff = freq * (1.0f - tt) + 0.25f * freq * tt;
    float ang = ((float)pos * eff) * 1.1386294361119891f;
    float sv = sinf(ang), cv = cosf(ang);
    int b = m >> 11, s = m & 2047;
    u16* o = Out + (((size_t)(b * nh + hh)) * 2048 + s) * 64;
    o[d]      = f2bf(x1 * cv - x2 * sv);
    o[d + 32] = f2bf(x2 * cv + x1 * sv);
}

// ---------------------------------------------------------------------------
// V: bf16 [B*S, 3072] (cols 2560..3071) -> bf16 transposed [B*NKV, 64, S]
// ---------------------------------------------------------------------------
__global__ __launch_bounds__(256)
void v_transpose(const u16* __restrict__ Vt, u16* __restrict__ VbT)
{
    __shared__ u16 tile[64][66];
    int s0 = blockIdx.x * 64;
    int bkv = blockIdx.y;
    int b = bkv >> 3, kv = bkv & 7;
    int t = threadIdx.x;
#pragma unroll
    for (int it = 0; it < 16; ++it) {
        int idx = t + it * 256;
        int s = idx >> 6, d = idx & 63;
        tile[s][d] = Vt[((size_t)(b * 2048 + s0 + s)) * 3072 + 2560 + kv * 64 + d];
    }
    __syncthreads();
#pragma unroll
    for (int it = 0; it < 16; ++it) {
        int idx = t + it * 256;
        int d = idx >> 6, s = idx & 63;
        VbT[((size_t)(bkv * 64 + d)) * 2048 + s0 + s] = tile[s][d];
    }
}

// ---------------------------------------------------------------------------
// Sliding-window attention, 64-query tiles.
// Block = (b, kv, 64-query tile); 4 waves = 4 heads of the group.
// Window: 192 keys starting at ks0 = q0-128 (8-aligned -> 16B global loads).
// Allowed keys for local query qi: qi < kk <= qi+128, ks0+kk >= 0.
// Per wave: 4 x [ QK^T (24 mfma) -> quad-shuffle softmax+sink -> P to
// wave-private LDS -> PV (24 mfma) -> ctx ].
// ---------------------------------------------------------------------------
__global__ __launch_bounds__(256, 2)
void attn_win(const u16* __restrict__ Qb, const u16* __restrict__ Kb,
              const u16* __restrict__ VbT, const float* __restrict__ sinks,
              u16* __restrict__ Ctx)
{
    __shared__ u16 Ks[192 * 72];      // K rows  [key][d],  stride 72
    __shared__ u16 Vs[64 * 200];      // V^T     [d][key],  stride 200
    __shared__ u16 Pb[4 * 16 * 200];  // per-wave P tile [16 q][192 key]
    const int S = 2048;
    const int tid = threadIdx.x;
    const int lane = tid & 63;
    const int w = tid >> 6;
    const int cc = lane & 15, qq = lane >> 4;
    const int blk = blockIdx.x;
    const int qt = blk & 31;
    const int bkv = blk >> 5;
    const int b = bkv >> 3, kv = bkv & 7;
    const int q0 = qt * 64;
    const int ks0 = q0 - 128;
    const int h = kv * 4 + w;

    // stage K: 192 rows x 64 d, 16B chunks
    const u16* KbBase = Kb + (size_t)bkv * S * 64;
#pragma unroll
    for (int it = 0; it < 6; ++it) {
        int c = tid + it * 256;
        int kk = c >> 3, c8 = (c & 7) << 3;
        int sk = ks0 + kk;
        us8 v = {0, 0, 0, 0, 0, 0, 0, 0};
        if (sk >= 0) v = *(const us8*)(KbBase + (size_t)sk * 64 + c8);
        *(us8*)&Ks[kk * 72 + c8] = v;
    }
    // stage V^T: 64 rows x 192 keys (sk multiple of 8 per chunk; no straddle)
    const u16* VtBase = VbT + (size_t)bkv * 64 * S;
#pragma unroll
    for (int it = 0; it < 6; ++it) {
        int c = tid + it * 256;
        int d = c / 24, kc = c % 24;
        int kk0 = kc << 3;
        int sk = ks0 + kk0;
        us8 v = {0, 0, 0, 0, 0, 0, 0, 0};
        if (sk >= 0) v = *(const us8*)(VtBase + (size_t)d * S + sk);
        *(us8*)&Vs[d * 200 + kk0] = v;
    }
    __syncthreads();

    const float sinkv = sinks[h];
    u16* Pw = &Pb[w * 3200];
    const u16* Qbase = Qb + ((size_t)(b * 32 + h) * S + q0) * 64;

    for (int i = 0; i < 4; ++i) {
        const u16* Qrow = Qbase + (size_t)(i * 16 + cc) * 64;
        bf16x8 aq0 = *(const bf16x8*)(Qrow + qq * 8);
        bf16x8 aq1 = *(const bf16x8*)(Qrow + 32 + qq * 8);

        f32x4 sc[12];
#pragma unroll
        for (int j = 0; j < 12; j++) sc[j] = (f32x4){0.f, 0.f, 0.f, 0.f};
#pragma unroll
        for (int j = 0; j < 12; j++) {
            bf16x8 b0 = *(const bf16x8*)&Ks[(j * 16 + cc) * 72 + qq * 8];
            bf16x8 b1 = *(const bf16x8*)&Ks[(j * 16 + cc) * 72 + 32 + qq * 8];
            sc[j] = mfma16(aq0, b0, sc[j]);
            sc[j] = mfma16(aq1, b1, sc[j]);
        }

#pragma unroll
        for (int r = 0; r < 4; ++r) {
            int qi = i * 16 + qq * 4 + r;
            float sval[12];
            float mx = -3.0e38f;
#pragma unroll
            for (int j = 0; j < 12; j++) {
                int kk = j * 16 + cc;
                float s = sc[j][r] * 0.125f;   // 1/sqrt(64)
                bool ok = (kk > qi) && (kk <= qi + 128) && (ks0 + kk >= 0);
                s = ok ? s : -3.0e38f;
                sval[j] = s;
                mx = fmaxf(mx, s);
            }
#pragma unroll
            for (int off = 1; off < 16; off <<= 1) mx = fmaxf(mx, __shfl_xor(mx, off));
            mx = fmaxf(mx, sinkv);
            float sum = 0.f;
#pragma unroll
            for (int j = 0; j < 12; j++) {
                float p = __expf(sval[j] - mx);
                sval[j] = p;
                sum += p;
            }
#pragma unroll
            for (int off = 1; off < 16; off <<= 1) sum += __shfl_xor(sum, off);
            float rden = 1.0f / (sum + __expf(sinkv - mx));
#pragma unroll
            for (int j = 0; j < 12; j++)
                Pw[(qq * 4 + r) * 200 + j * 16 + cc] = f2bf(sval[j] * rden);
        }

        // PV: 16 queries x 64 dims, K=192 -> 6 k-steps
        f32x4 o[4];
#pragma unroll
        for (int jt = 0; jt < 4; jt++) o[jt] = (f32x4){0.f, 0.f, 0.f, 0.f};
#pragma unroll
        for (int ks = 0; ks < 6; ks++) {
            bf16x8 ap = *(const bf16x8*)&Pw[cc * 200 + ks * 32 + qq * 8];
#pragma unroll
            for (int jt = 0; jt < 4; jt++) {
                bf16x8 bv = *(const bf16x8*)&Vs[(jt * 16 + cc) * 200 + ks * 32 + qq * 8];
                o[jt] = mfma16(ap, bv, o[jt]);
            }
        }
#pragma unroll
        for (int jt = 0; jt < 4; jt++) {
#pragma unroll
            for (int r = 0; r < 4; r++) {
                size_t off = ((size_t)(b * S + q0 + i * 16 + qq * 4 + r)) * 2048
                           + h * 64 + jt * 16 + cc;
                Ctx[off] = f2bf(o[jt][r]);
            }
        }
    }
}

// ---------------------------------------------------------------------------
extern "C" void kernel_launch(void* const* d_in, const int* in_sizes, int n_in,
                              void* d_out, int out_size, void* d_ws, size_t ws_size,
                              hipStream_t stream)
{
    const float* x    = (const float*)d_in[0];
    const float* Wq   = (const float*)d_in[1];
    const float* bq   = (const float*)d_in[2];
    const float* Wk   = (const float*)d_in[3];
    const float* bk   = (const float*)d_in[4];
    const float* Wv   = (const float*)d_in[5];
    const float* bv   = (const float*)d_in[6];
    const float* Wo   = (const float*)d_in[7];
    const float* bo   = (const float*)d_in[8];
    const float* sinks = (const float*)d_in[9];
    const int*   pid  = (const int*)d_in[10];
    float* out = (float*)d_out;

    char* ws = (char*)d_ws;
    u16*   Wqkvb = (u16*)ws;                         // 12,582,912 B
    u16*   Wob   = (u16*)(ws + 12582912);            //  8,388,608 B
    u16*   xQb   = (u16*)(ws + 20971520);            // 16,777,216 B (xb, then Qb)
    u16*   QKV   = (u16*)(ws + 37748736);            // 25,165,824 B (then Ctx)
    u16*   Kb    = (u16*)(ws + 62914560);            //  4,194,304 B
    u16*   VbT   = (u16*)(ws + 67108864);            //  4,194,304 B
    float* bqkv  = (float*)(ws + 71303168);          //     12,288 B

    const int M = 4096;
    pack_bf16<<<8192, 256, 0, stream>>>(x,  xQb, 8388608);
    pack_bf16<<<4096, 256, 0, stream>>>(Wq, Wqkvb, 4194304);
    pack_bf16<<<1024, 256, 0, stream>>>(Wk, Wqkvb + 4194304, 1048576);
    pack_bf16<<<1024, 256, 0, stream>>>(Wv, Wqkvb + 5242880, 1048576);
    pack_bf16<<<4096, 256, 0, stream>>>(Wo, Wob, 4194304);
    concat_bias<<<12, 256, 0, stream>>>(bq, bk, bv, bqkv);

    gemm_bb<1><<<dim3(24, 32), 256, 0, stream>>>(xQb, Wqkvb, bqkv, QKV, M, 3072, 2048);

    rope_qk<<<16384, 256, 0, stream>>>(QKV, pid, xQb, 32, 5, 0);      // Qb aliases xb
    rope_qk<<<4096,  256, 0, stream>>>(QKV, pid, Kb, 8, 3, 2048);
    v_transpose<<<dim3(32, 16), 256, 0, stream>>>(QKV, VbT);

    attn_win<<<512, 256, 0, stream>>>(xQb, Kb, VbT, sinks, QKV);      // Ctx aliases QKV

    gemm_bb<0><<<dim3(16, 32), 256, 0, stream>>>(QKV, Wob, bo, out, M, 2048, 2048);
}